// Round 22
// baseline (96.122 us; speedup 1.0000x reference)
//
#include <hip/hip_runtime.h>
#include <hip/hip_bf16.h>
#include <stdint.h>

#define EMBED 1024
#define HEADS 16
#define HDIM 64
#define BATCH 2
#define SEQ 2048
#define NROWS (BATCH*SEQ)

typedef __attribute__((ext_vector_type(8))) short short8;
typedef __attribute__((ext_vector_type(4))) float f32x4;

#define LOG2E 1.44269504088896f

__device__ __forceinline__ unsigned short f2bf(float f) {
    __hip_bfloat16 b = __float2bfloat16(f);
    return *reinterpret_cast<unsigned short*>(&b);
}

__device__ __forceinline__ unsigned cvt_pk_bf16(float lo, float hi) {
    unsigned r;
    asm("v_cvt_pk_bf16_f32 %0, %1, %2" : "=v"(r) : "v"(lo), "v"(hi));
    return r;
}

__device__ __forceinline__ short8 mk8(unsigned a, unsigned b, unsigned c, unsigned d) {
    union { unsigned u[4]; short8 s; } x;
    x.u[0] = a; x.u[1] = b; x.u[2] = c; x.u[3] = d;
    return x.s;
}

__device__ __forceinline__ void g2l16(const void* g, void* l) {
    __builtin_amdgcn_global_load_lds(
        (const __attribute__((address_space(1))) unsigned int*)g,
        (__attribute__((address_space(3))) unsigned int*)l, 16, 0, 0);
}

// ------- fused prep: transpose+cast 4 weight matrices AND cast x ------------
__global__ void prep_kernel(const float* __restrict__ x,
                            unsigned short* __restrict__ xb,
                            const float* __restrict__ W0,
                            const float* __restrict__ W1,
                            const float* __restrict__ W2,
                            const float* __restrict__ W3,
                            unsigned short* __restrict__ dst) {
    __shared__ float tile[32][33];
    const int id = blockIdx.x;
    const int t = threadIdx.x;
    if (id < 4096) {
        const int z = id >> 10;
        const int by = (id >> 5) & 31;
        const int bx = id & 31;
        const float* W = (z == 0) ? W0 : (z == 1) ? W1 : (z == 2) ? W2 : W3;
        unsigned short* Wt = dst + (size_t)z * EMBED * EMBED;
        const int tx = t & 31, ty = t >> 5;
#pragma unroll
        for (int r = 0; r < 4; r++) {
            int i = by * 32 + ty + r * 8;
            int o = bx * 32 + tx;
            tile[ty + r * 8][tx] = W[(size_t)i * EMBED + o];
        }
        __syncthreads();
        int i2 = by * 32 + tx;
#pragma unroll
        for (int r = 0; r < 4; r++) {
            int o2 = bx * 32 + ty + r * 8;
            Wt[(size_t)o2 * EMBED + i2] = f2bf(tile[tx][ty + r * 8]);
        }
    } else {
        int i = (id - 4096) * 256 + t;
        float4 v = reinterpret_cast<const float4*>(x)[i];
        ushort4 o;
        o.x = f2bf(v.x); o.y = f2bf(v.y); o.z = f2bf(v.z); o.w = f2bf(v.w);
        reinterpret_cast<ushort4*>(xb)[i] = o;
    }
}

// ---------------- GEMM: C[M][N] = A[M][K] * B[N][K]^T  (bf16 in, fp32 acc) --
template<int MODE, int BM, int BN, int PIPE>
__global__ __launch_bounds__(256)
void gemm_kernel(const unsigned short* __restrict__ A,
                 const unsigned short* __restrict__ B,
                 int K,
                 unsigned short* __restrict__ Qo,
                 unsigned short* __restrict__ Ko,
                 unsigned short* __restrict__ Vto,
                 const float* __restrict__ bq,
                 const float* __restrict__ bk,
                 const float* __restrict__ bvv,
                 float* __restrict__ Co,
                 const float* __restrict__ bo) {
    constexpr int AI = BM / 32;
    constexpr int BJ = BN / 32;
    constexpr int NBUF = PIPE ? 2 : 1;
    __shared__ __attribute__((aligned(16))) unsigned short As[NBUF][BM * 64];
    __shared__ __attribute__((aligned(16))) unsigned short Bs[NBUF][BN * 64];
    const int t = threadIdx.x;
    const int lane = t & 63;
    const int w = t >> 6;
    const int wr = w >> 1, wc = w & 1;
    const int l15 = lane & 15, l16 = lane >> 4;

    int bx, by;
    {
        const int xcd = blockIdx.x & 7;
        const int r = blockIdx.x >> 3;
        if (MODE == 0) {                    // 24x32 tiles, 12x8 chunks
            bx = (xcd & 1) * 12 + r % 12;
            by = (xcd >> 1) * 8 + r / 12;
        } else {                            // 16x64 tiles, 16x8 chunks
            bx = r & 15;
            by = xcd * 8 + (r >> 4);
        }
    }
    const int m0 = by * BM;
    const int n0 = bx * BN;

    f32x4 acc[AI][BJ];
#pragma unroll
    for (int i = 0; i < AI; i++)
#pragma unroll
        for (int j = 0; j < BJ; j++) acc[i][j] = (f32x4){0.f, 0.f, 0.f, 0.f};

    auto stage = [&](int k0, int buf) {
#pragma unroll
        for (int i = 0; i < BM / 32; i++) {
            int c = i * 256 + t;
            int row = c >> 3;
            int lc = (c & 7) ^ (row & 7);
            g2l16(A + (size_t)(m0 + row) * K + k0 + lc * 8,
                  As[buf] + (size_t)(i * 256 + (t & ~63)) * 8);
        }
#pragma unroll
        for (int i = 0; i < BN / 32; i++) {
            int c = i * 256 + t;
            int row = c >> 3;
            int lc = (c & 7) ^ (row & 7);
            g2l16(B + (size_t)(n0 + row) * K + k0 + lc * 8,
                  Bs[buf] + (size_t)(i * 256 + (t & ~63)) * 8);
        }
    };

    auto compute = [&](int buf) {
#pragma unroll
        for (int kk = 0; kk < 2; kk++) {
            short8 a[AI], b[BJ];
#pragma unroll
            for (int ai = 0; ai < AI; ai++) {
                int row = wr * (BM / 2) + ai * 16 + l15;
                int ch = kk * 4 + l16;
                a[ai] = *reinterpret_cast<const short8*>(
                    As[buf] + row * 64 + ((ch ^ (row & 7)) << 3));
            }
#pragma unroll
            for (int bj = 0; bj < BJ; bj++) {
                int row = wc * (BN / 2) + bj * 16 + l15;
                int ch = kk * 4 + l16;
                b[bj] = *reinterpret_cast<const short8*>(
                    Bs[buf] + row * 64 + ((ch ^ (row & 7)) << 3));
            }
            __builtin_amdgcn_s_setprio(1);
#pragma unroll
            for (int ai = 0; ai < AI; ai++)
#pragma unroll
                for (int bj = 0; bj < BJ; bj++)
                    acc[ai][bj] = __builtin_amdgcn_mfma_f32_16x16x32_bf16(
                        a[ai], b[bj], acc[ai][bj], 0, 0, 0);
            __builtin_amdgcn_s_setprio(0);
        }
    };

    if (PIPE) {
        const int ntk = K >> 6;
        stage(0, 0);
        asm volatile("s_waitcnt vmcnt(0)" ::: "memory");
        __builtin_amdgcn_s_barrier();
        asm volatile("" ::: "memory");
        for (int tk = 0; tk < ntk; tk++) {
            if (tk + 1 < ntk) stage((tk + 1) << 6, (tk + 1) & 1);
            compute(tk & 1);
            asm volatile("s_waitcnt vmcnt(0)" ::: "memory");
            __builtin_amdgcn_s_barrier();
            asm volatile("" ::: "memory");
        }
    } else {
        for (int k0 = 0; k0 < K; k0 += 64) {
            __syncthreads();
            stage(k0, 0);
            __syncthreads();
            compute(0);
        }
    }

    if (MODE == 0) {
        const int which = n0 >> 10;        // 0=Q 1=K 2=V
        const int coln = n0 & 1023;
        const float* bias = which == 0 ? bq : (which == 1 ? bk : bvv);
        const float scale = which == 0 ? 0.125f * LOG2E : 1.0f;
#pragma unroll
        for (int ai = 0; ai < AI; ai++) {
            int rowb = m0 + wr * (BM / 2) + ai * 16 + l16 * 4;
            int b_ = rowb >> 11;
            int s = rowb & 2047;
#pragma unroll
            for (int bj = 0; bj < BJ; bj++) {
                int col = coln + wc * (BN / 2) + bj * 16 + l15;
                float bsv = bias[col];
                int h = col >> 6, d = col & 63;
                if (which < 2) {
                    unsigned short* dst = (which == 0) ? Qo : Ko;
                    size_t base = ((size_t)(b_ * HEADS + h)) * SEQ * HDIM;
#pragma unroll
                    for (int r = 0; r < 4; r++) {
                        float v = (acc[ai][bj][r] + bsv) * scale;
                        dst[base + (size_t)(s + r) * HDIM + d] = f2bf(v);
                    }
                } else {
                    ushort4 pk;
                    pk.x = f2bf(acc[ai][bj][0] + bsv);
                    pk.y = f2bf(acc[ai][bj][1] + bsv);
                    pk.z = f2bf(acc[ai][bj][2] + bsv);
                    pk.w = f2bf(acc[ai][bj][3] + bsv);
                    int cs = (s >> 2) & 15;
                    int ps = (cs & 8) | ((cs & 3) << 1) | ((cs >> 2) & 1);
                    size_t off = ((size_t)(b_ * HEADS + h) * HDIM + d) * SEQ +
                                 (size_t)((s & ~63) | (ps << 2));
                    *reinterpret_cast<ushort4*>(Vto + off) = pk;
                }
            }
        }
    } else {
#pragma unroll
        for (int ai = 0; ai < AI; ai++) {
            int rowb = m0 + wr * (BM / 2) + ai * 16 + l16 * 4;
#pragma unroll
            for (int bj = 0; bj < BJ; bj++) {
                int col = n0 + wc * (BN / 2) + bj * 16 + l15;
                float bsv = bo[col];
#pragma unroll
                for (int r = 0; r < 4; r++)
                    Co[(size_t)(rowb + r) * EMBED + col] = acc[ai][bj][r] + bsv;
            }
        }
    }
}

// ---------------- causal flash attention (in-block 2-way KV split) ----------
// Round-19 verified version (~38 us, 90.89 total): shuffle-free common-path
// softmax, per-lane l partials, hoisted V ds_reads, P in registers via
// cvt_pk + chunk-permuted V. THIS ROUND: heavy-first qi mapping (bijective;
// co-scheduled pairs (id, id+512) still sum to 33 tiles).
__device__ __forceinline__ void stage_kv(const unsigned short* __restrict__ Kg,
                                         const unsigned short* __restrict__ Vg,
                                         int kv0, unsigned short* Ksb,
                                         unsigned short* Vsb, int tl) {
#pragma unroll
    for (int i = 0; i < 4; i++) {          // K tile [64 keys][64 d]
        int c = i * 128 + tl;
        int row = c >> 3;
        int lc = (c & 7) ^ (row & 7);
        g2l16(Kg + (size_t)(kv0 + row) * HDIM + lc * 8,
              Ksb + (i * 128 + (tl & ~63)) * 8);
    }
#pragma unroll
    for (int i = 0; i < 4; i++) {          // V^T tile [64 d][64 keys']
        int c = i * 128 + tl;
        int d = c >> 3;
        int lc = (c & 7) ^ (d & 7);
        g2l16(Vg + (size_t)d * SEQ + kv0 + lc * 8,
              Vsb + (i * 128 + (tl & ~63)) * 8);
    }
}

__global__ __launch_bounds__(256, 2)
void attn_kernel(const unsigned short* __restrict__ Q,
                 const unsigned short* __restrict__ Kk,
                 const unsigned short* __restrict__ Vt,
                 unsigned short* __restrict__ O) {
    __shared__ __attribute__((aligned(16))) unsigned short Ks[4][64 * 64];
    __shared__ __attribute__((aligned(16))) unsigned short Vs[4][64 * 64];

    const int t = threadIdx.x;
    const int lane = t & 63;
    const int w = t >> 6;
    const int wq = w >> 1;            // q-half
    const int wk = w & 1;             // KV way (tile parity)
    const int l15 = lane & 15, l16 = lane >> 4;

    const int id = blockIdx.x;
    const int xcd = id & 7;
    const int u = id >> 3;             // 0..127 within XCD
    const int bh = xcd * 4 + (u & 3);  // 4 heads per XCD -> 2 MB K/V in L2
    const int su = u >> 2;             // 0..31
    // heavy-first, bijective; pairs (su, su+16) give qi + qi' = 31
    const int qi = (su < 16) ? (31 - su) : (su - 16);
    const int q0 = qi * 64;
    const size_t base = (size_t)bh * SEQ * HDIM;
    const unsigned short* Kg = Kk + base;
    const unsigned short* Vg = Vt + base;
    const int qrow0 = q0 + wq * 32;

    short8 qf[2][2];
    {
        const unsigned short* Qg = Q + base + (size_t)qrow0 * HDIM;
#pragma unroll
        for (int qb = 0; qb < 2; qb++)
#pragma unroll
            for (int kc = 0; kc < 2; kc++)
                qf[qb][kc] = *reinterpret_cast<const short8*>(
                    Qg + (qb * 16 + l15) * HDIM + (kc * 4 + l16) * 8);
    }

    f32x4 oacc[2][4];
#pragma unroll
    for (int qb = 0; qb < 2; qb++)
#pragma unroll
        for (int nd = 0; nd < 4; nd++) oacc[qb][nd] = (f32x4){0.f, 0.f, 0.f, 0.f};
    float m_run[2] = {-1e30f, -1e30f};
    float l_run[2] = {0.f, 0.f};          // per-lane partial sums

    const int nt = qi + 1;
    const int nsuper = (nt + 1) >> 1;

    auto stagepair = [&](int ta, int tb) {
        if (t < 128) {
            if (ta < nt) stage_kv(Kg, Vg, ta * 64, Ks[ta & 3], Vs[ta & 3], t);
        } else {
            if (tb < nt) stage_kv(Kg, Vg, tb * 64, Ks[tb & 3], Vs[tb & 3], t - 128);
        }
    };

    auto qkt = [&](f32x4 (&sc)[2][4], const unsigned short* Kb) {
#pragma unroll
        for (int qb = 0; qb < 2; qb++)
#pragma unroll
            for (int kb = 0; kb < 4; kb++) sc[qb][kb] = (f32x4){0.f, 0.f, 0.f, 0.f};
#pragma unroll
        for (int kc = 0; kc < 2; kc++) {
            short8 ka[4];
#pragma unroll
            for (int kb = 0; kb < 4; kb++) {
                int row = kb * 16 + l15;
                ka[kb] = *reinterpret_cast<const short8*>(
                    Kb + row * 64 + (((kc * 4 + l16) ^ (row & 7)) << 3));
            }
            __builtin_amdgcn_s_setprio(1);
#pragma unroll
            for (int qb = 0; qb < 2; qb++)
#pragma unroll
                for (int kb = 0; kb < 4; kb++)
                    sc[qb][kb] = __builtin_amdgcn_mfma_f32_16x16x32_bf16(
                        ka[kb], qf[qb][kc], sc[qb][kb], 0, 0, 0);
            __builtin_amdgcn_s_setprio(0);
        }
    };

    auto softmax_pv = [&](f32x4 (&sc)[2][4], const unsigned short* Vb, bool diag) {
        // hoisted V-fragment reads: latency hides under the softmax chain
        short8 vb[2][4];
#pragma unroll
        for (int m = 0; m < 2; m++)
#pragma unroll
            for (int nd = 0; nd < 4; nd++) {
                int row = nd * 16 + l15;
                vb[m][nd] = *reinterpret_cast<const short8*>(
                    Vb + row * 64 + (((m * 4 + l16) ^ (row & 7)) << 3));
            }
        if (diag) {
#pragma unroll
            for (int qb = 0; qb < 2; qb++) {
                const int qloc = wq * 32 + qb * 16 + l15;
#pragma unroll
                for (int kb = 0; kb < 4; kb++)
#pragma unroll
                    for (int r = 0; r < 4; r++) {
                        int kloc = kb * 16 + l16 * 4 + r;
                        sc[qb][kb][r] = (kloc > qloc) ? -1e30f : sc[qb][kb][r];
                    }
            }
        }
        float vmax[2];
        bool need = false;
#pragma unroll
        for (int qb = 0; qb < 2; qb++) {
            float mx = -1e30f;
#pragma unroll
            for (int kb = 0; kb < 4; kb++)
                mx = fmaxf(mx, fmaxf(fmaxf(sc[qb][kb][0], sc[qb][kb][1]),
                                     fmaxf(sc[qb][kb][2], sc[qb][kb][3])));
            vmax[qb] = mx;
            need = need || (mx > m_run[qb] + 8.0f);
        }
        if (__any(need)) {                 // rare: cross-lane work only here
#pragma unroll
            for (int qb = 0; qb < 2; qb++) {
                float mx = vmax[qb];
                mx = fmaxf(mx, __shfl_xor(mx, 16));
                mx = fmaxf(mx, __shfl_xor(mx, 32));
                float mn = fmaxf(m_run[qb], mx);
                float sf = __builtin_amdgcn_exp2f(m_run[qb] - mn);
                m_run[qb] = mn;
                l_run[qb] *= sf;
#pragma unroll
                for (int r = 0; r < 4; r++) {
                    float sfr = __shfl(sf, l16 * 4 + r);
#pragma unroll
                    for (int nd = 0; nd < 4; nd++) oacc[qb][nd][r] *= sfr;
                }
            }
        }
        short8 pa[2][2];
#pragma unroll
        for (int qb = 0; qb < 2; qb++) {
            float p[4][4];
            float ps = 0.f;
#pragma unroll
            for (int kb = 0; kb < 4; kb++)
#pragma unroll
                for (int r = 0; r < 4; r++) {
                    p[kb][r] = __builtin_amdgcn_exp2f(sc[qb][kb][r] - m_run[qb]);
                    ps += p[kb][r];
                }
            pa[qb][0] = mk8(cvt_pk_bf16(p[0][0], p[0][1]),
                            cvt_pk_bf16(p[0][2], p[0][3]),
                            cvt_pk_bf16(p[1][0], p[1][1]),
                            cvt_pk_bf16(p[1][2], p[1][3]));
            pa[qb][1] = mk8(cvt_pk_bf16(p[2][0], p[2][1]),
                            cvt_pk_bf16(p[2][2], p[2][3]),
                            cvt_pk_bf16(p[3][0], p[3][1]),
                            cvt_pk_bf16(p[3][2], p[3][3]));
            l_run[qb] += ps;               // per-lane partial; no shuffles
        }
        __builtin_amdgcn_s_setprio(1);
#pragma unroll
        for (int m = 0; m < 2; m++)
#pragma unroll
            for (int qb = 0; qb < 2; qb++)
#pragma unroll
                for (int nd = 0; nd < 4; nd++)
                    oacc[qb][nd] = __builtin_amdgcn_mfma_f32_16x16x32_bf16(
                        pa[qb][m], vb[m][nd], oacc[qb][nd], 0, 0, 0);
        __builtin_amdgcn_s_setprio(0);
    };

    f32x4 sc[2][4];

    stagepair(0, 1);
    asm volatile("s_waitcnt vmcnt(0)" ::: "memory");
    __builtin_amdgcn_s_barrier();
    asm volatile("" ::: "memory");
    stagepair(2, 3);
    int myt = wk;
    if (myt < nt) qkt(sc, Ks[myt & 3]);

    for (int j = 1; j < nsuper; j++) {
        if (myt < nt) softmax_pv(sc, Vs[myt & 3], false);
        asm volatile("s_waitcnt vmcnt(0)" ::: "memory");
        __builtin_amdgcn_s_barrier();
        asm volatile("" ::: "memory");
        stagepair(2 * j + 2, 2 * j + 3);
        int tc = 2 * j + wk;
        if (tc < nt) qkt(sc, Ks[tc & 3]);
        myt = tc;
    }
    if (myt < nt) softmax_pv(sc, Vs[myt & 3], myt == nt - 1);

    // ---- cross-way merge via LDS (aliases staging buffers; reads done) ----
    __syncthreads();
    float* po = reinterpret_cast<float*>(&Ks[0][0]);   // way-1 oacc, 16 KB
    float* pml = reinterpret_cast<float*>(&Vs[0][0]);  // way-1 m,l (per-lane)
    if (wk == 1) {
#pragma unroll
        for (int qb = 0; qb < 2; qb++) {
#pragma unroll
            for (int nd = 0; nd < 4; nd++)
                reinterpret_cast<f32x4*>(po)[(((wq << 1) | qb) * 4 + nd) * 64 + lane] =
                    oacc[qb][nd];
            pml[((((wq << 1) | qb) * 64) + lane) * 2]     = m_run[qb];
            pml[((((wq << 1) | qb) * 64) + lane) * 2 + 1] = l_run[qb];
        }
    }
    __syncthreads();
    if (wk == 0) {
        const int b_ = bh >> 4, h = bh & 15;
#pragma unroll
        for (int qb = 0; qb < 2; qb++) {
            float m1 = pml[((((wq << 1) | qb) * 64) + lane) * 2];
            float l1 = pml[((((wq << 1) | qb) * 64) + lane) * 2 + 1];
            float ms = fmaxf(m_run[qb], m1);
            float a0 = __builtin_amdgcn_exp2f(m_run[qb] - ms);
            float a1 = __builtin_amdgcn_exp2f(m1 - ms);
            float lmp = l_run[qb] * a0 + l1 * a1;
            lmp += __shfl_xor(lmp, 16);
            lmp += __shfl_xor(lmp, 32);
            f32x4 o1[4];
#pragma unroll
            for (int nd = 0; nd < 4; nd++)
                o1[nd] = reinterpret_cast<f32x4*>(po)[(((wq << 1) | qb) * 4 + nd) * 64 + lane];
            float li = 1.0f / lmp;
#pragma unroll
            for (int r = 0; r < 4; r++) {
                float a0r = __shfl(a0, l16 * 4 + r);
                float a1r = __shfl(a1, l16 * 4 + r);
                float lir = __shfl(li, l16 * 4 + r);
                int row = b_ * SEQ + qrow0 + qb * 16 + l16 * 4 + r;
#pragma unroll
                for (int nd = 0; nd < 4; nd++) {
                    float v = oacc[qb][nd][r] * a0r + o1[nd][r] * a1r;
                    O[(size_t)row * EMBED + h * 64 + nd * 16 + l15] = f2bf(v * lir);
                }
            }
        }
    }
}

extern "C" void kernel_launch(void* const* d_in, const int* in_sizes, int n_in,
                              void* d_out, int out_size, void* d_ws, size_t ws_size,
                              hipStream_t stream) {
    (void)in_sizes; (void)n_in; (void)out_size; (void)ws_size;
    const float* x  = (const float*)d_in[0];
    const float* Wq = (const float*)d_in[1];
    const float* bq = (const float*)d_in[2];
    const float* Wk = (const float*)d_in[3];
    const float* bk = (const float*)d_in[4];
    const float* Wv = (const float*)d_in[5];
    const float* bv = (const float*)d_in[6];
    const float* Wo = (const float*)d_in[7];
    const float* bo = (const float*)d_in[8];
    float* out = (float*)d_out;

    unsigned short* xb   = (unsigned short*)d_ws;
    unsigned short* Wqkv = xb + (size_t)NROWS * EMBED;          // [4][1024][1024]
    unsigned short* Wot  = Wqkv + (size_t)3 * EMBED * EMBED;    // = Wqkv[3]
    unsigned short* Qb   = Wot + (size_t)EMBED * EMBED;         // [b,h,s,d]
    unsigned short* Kb   = Qb + (size_t)NROWS * EMBED;
    unsigned short* Vtb  = Kb + (size_t)NROWS * EMBED;          // [b,h,d,s']
    unsigned short* attn = Vtb + (size_t)NROWS * EMBED;         // [b*s][1024]

    prep_kernel<<<8192, 256, 0, stream>>>(x, xb, Wq, Wk, Wv, Wo, Wqkv);

    gemm_kernel<0, 128, 128, 0><<<768, 256, 0, stream>>>(
        xb, Wqkv, EMBED, Qb, Kb, Vtb, bq, bk, bv, nullptr, nullptr);

    attn_kernel<<<1024, 256, 0, stream>>>(Qb, Kb, Vtb, attn);

    gemm_kernel<1, 64, 64, 1><<<1024, 256, 0, stream>>>(
        attn, Wot, EMBED, nullptr, nullptr, nullptr, nullptr, nullptr, nullptr,
        out, bo);
}

// Round 23
// 90.376 us; speedup vs baseline: 1.0636x; 1.0636x over previous
//
#include <hip/hip_runtime.h>
#include <hip/hip_bf16.h>
#include <stdint.h>

#define EMBED 1024
#define HEADS 16
#define HDIM 64
#define BATCH 2
#define SEQ 2048
#define NROWS (BATCH*SEQ)

typedef __attribute__((ext_vector_type(8))) short short8;
typedef __attribute__((ext_vector_type(4))) float f32x4;

#define LOG2E 1.44269504088896f

__device__ __forceinline__ unsigned short f2bf(float f) {
    __hip_bfloat16 b = __float2bfloat16(f);
    return *reinterpret_cast<unsigned short*>(&b);
}

__device__ __forceinline__ unsigned cvt_pk_bf16(float lo, float hi) {
    unsigned r;
    asm("v_cvt_pk_bf16_f32 %0, %1, %2" : "=v"(r) : "v"(lo), "v"(hi));
    return r;
}

__device__ __forceinline__ short8 mk8(unsigned a, unsigned b, unsigned c, unsigned d) {
    union { unsigned u[4]; short8 s; } x;
    x.u[0] = a; x.u[1] = b; x.u[2] = c; x.u[3] = d;
    return x.s;
}

__device__ __forceinline__ void g2l16(const void* g, void* l) {
    __builtin_amdgcn_global_load_lds(
        (const __attribute__((address_space(1))) unsigned int*)g,
        (__attribute__((address_space(3))) unsigned int*)l, 16, 0, 0);
}

// ------- fused prep: transpose+cast 4 weight matrices AND cast x ------------
__global__ void prep_kernel(const float* __restrict__ x,
                            unsigned short* __restrict__ xb,
                            const float* __restrict__ W0,
                            const float* __restrict__ W1,
                            const float* __restrict__ W2,
                            const float* __restrict__ W3,
                            unsigned short* __restrict__ dst) {
    __shared__ float tile[32][33];
    const int id = blockIdx.x;
    const int t = threadIdx.x;
    if (id < 4096) {
        const int z = id >> 10;
        const int by = (id >> 5) & 31;
        const int bx = id & 31;
        const float* W = (z == 0) ? W0 : (z == 1) ? W1 : (z == 2) ? W2 : W3;
        unsigned short* Wt = dst + (size_t)z * EMBED * EMBED;
        const int tx = t & 31, ty = t >> 5;
#pragma unroll
        for (int r = 0; r < 4; r++) {
            int i = by * 32 + ty + r * 8;
            int o = bx * 32 + tx;
            tile[ty + r * 8][tx] = W[(size_t)i * EMBED + o];
        }
        __syncthreads();
        int i2 = by * 32 + tx;
#pragma unroll
        for (int r = 0; r < 4; r++) {
            int o2 = bx * 32 + ty + r * 8;
            Wt[(size_t)o2 * EMBED + i2] = f2bf(tile[tx][ty + r * 8]);
        }
    } else {
        int i = (id - 4096) * 256 + t;
        float4 v = reinterpret_cast<const float4*>(x)[i];
        ushort4 o;
        o.x = f2bf(v.x); o.y = f2bf(v.y); o.z = f2bf(v.z); o.w = f2bf(v.w);
        reinterpret_cast<ushort4*>(xb)[i] = o;
    }
}

// ---------------- GEMM: C[M][N] = A[M][K] * B[N][K]^T  (bf16 in, fp32 acc) --
template<int MODE, int BM, int BN, int PIPE>
__global__ __launch_bounds__(256)
void gemm_kernel(const unsigned short* __restrict__ A,
                 const unsigned short* __restrict__ B,
                 int K,
                 unsigned short* __restrict__ Qo,
                 unsigned short* __restrict__ Ko,
                 unsigned short* __restrict__ Vto,
                 const float* __restrict__ bq,
                 const float* __restrict__ bk,
                 const float* __restrict__ bvv,
                 float* __restrict__ Co,
                 const float* __restrict__ bo) {
    constexpr int AI = BM / 32;
    constexpr int BJ = BN / 32;
    constexpr int NBUF = PIPE ? 2 : 1;
    __shared__ __attribute__((aligned(16))) unsigned short As[NBUF][BM * 64];
    __shared__ __attribute__((aligned(16))) unsigned short Bs[NBUF][BN * 64];
    const int t = threadIdx.x;
    const int lane = t & 63;
    const int w = t >> 6;
    const int wr = w >> 1, wc = w & 1;
    const int l15 = lane & 15, l16 = lane >> 4;

    int bx, by;
    {
        const int xcd = blockIdx.x & 7;
        const int r = blockIdx.x >> 3;
        if (MODE == 0) {                    // 24x32 tiles, 12x8 chunks
            bx = (xcd & 1) * 12 + r % 12;
            by = (xcd >> 1) * 8 + r / 12;
        } else {                            // 16x64 tiles, 16x8 chunks
            bx = r & 15;
            by = xcd * 8 + (r >> 4);
        }
    }
    const int m0 = by * BM;
    const int n0 = bx * BN;

    f32x4 acc[AI][BJ];
#pragma unroll
    for (int i = 0; i < AI; i++)
#pragma unroll
        for (int j = 0; j < BJ; j++) acc[i][j] = (f32x4){0.f, 0.f, 0.f, 0.f};

    auto stage = [&](int k0, int buf) {
#pragma unroll
        for (int i = 0; i < BM / 32; i++) {
            int c = i * 256 + t;
            int row = c >> 3;
            int lc = (c & 7) ^ (row & 7);
            g2l16(A + (size_t)(m0 + row) * K + k0 + lc * 8,
                  As[buf] + (size_t)(i * 256 + (t & ~63)) * 8);
        }
#pragma unroll
        for (int i = 0; i < BN / 32; i++) {
            int c = i * 256 + t;
            int row = c >> 3;
            int lc = (c & 7) ^ (row & 7);
            g2l16(B + (size_t)(n0 + row) * K + k0 + lc * 8,
                  Bs[buf] + (size_t)(i * 256 + (t & ~63)) * 8);
        }
    };

    auto compute = [&](int buf) {
#pragma unroll
        for (int kk = 0; kk < 2; kk++) {
            short8 a[AI], b[BJ];
#pragma unroll
            for (int ai = 0; ai < AI; ai++) {
                int row = wr * (BM / 2) + ai * 16 + l15;
                int ch = kk * 4 + l16;
                a[ai] = *reinterpret_cast<const short8*>(
                    As[buf] + row * 64 + ((ch ^ (row & 7)) << 3));
            }
#pragma unroll
            for (int bj = 0; bj < BJ; bj++) {
                int row = wc * (BN / 2) + bj * 16 + l15;
                int ch = kk * 4 + l16;
                b[bj] = *reinterpret_cast<const short8*>(
                    Bs[buf] + row * 64 + ((ch ^ (row & 7)) << 3));
            }
            __builtin_amdgcn_s_setprio(1);
#pragma unroll
            for (int ai = 0; ai < AI; ai++)
#pragma unroll
                for (int bj = 0; bj < BJ; bj++)
                    acc[ai][bj] = __builtin_amdgcn_mfma_f32_16x16x32_bf16(
                        a[ai], b[bj], acc[ai][bj], 0, 0, 0);
            __builtin_amdgcn_s_setprio(0);
        }
    };

    if (PIPE) {
        const int ntk = K >> 6;
        stage(0, 0);
        asm volatile("s_waitcnt vmcnt(0)" ::: "memory");
        __builtin_amdgcn_s_barrier();
        asm volatile("" ::: "memory");
        for (int tk = 0; tk < ntk; tk++) {
            if (tk + 1 < ntk) stage((tk + 1) << 6, (tk + 1) & 1);
            compute(tk & 1);
            asm volatile("s_waitcnt vmcnt(0)" ::: "memory");
            __builtin_amdgcn_s_barrier();
            asm volatile("" ::: "memory");
        }
    } else {
        for (int k0 = 0; k0 < K; k0 += 64) {
            __syncthreads();
            stage(k0, 0);
            __syncthreads();
            compute(0);
        }
    }

    if (MODE == 0) {
        const int which = n0 >> 10;        // 0=Q 1=K 2=V
        const int coln = n0 & 1023;
        const float* bias = which == 0 ? bq : (which == 1 ? bk : bvv);
        const float scale = which == 0 ? 0.125f * LOG2E : 1.0f;
#pragma unroll
        for (int ai = 0; ai < AI; ai++) {
            int rowb = m0 + wr * (BM / 2) + ai * 16 + l16 * 4;
            int b_ = rowb >> 11;
            int s = rowb & 2047;
#pragma unroll
            for (int bj = 0; bj < BJ; bj++) {
                int col = coln + wc * (BN / 2) + bj * 16 + l15;
                float bsv = bias[col];
                int h = col >> 6, d = col & 63;
                if (which < 2) {
                    unsigned short* dst = (which == 0) ? Qo : Ko;
                    size_t base = ((size_t)(b_ * HEADS + h)) * SEQ * HDIM;
#pragma unroll
                    for (int r = 0; r < 4; r++) {
                        float v = (acc[ai][bj][r] + bsv) * scale;
                        dst[base + (size_t)(s + r) * HDIM + d] = f2bf(v);
                    }
                } else {
                    ushort4 pk;
                    pk.x = f2bf(acc[ai][bj][0] + bsv);
                    pk.y = f2bf(acc[ai][bj][1] + bsv);
                    pk.z = f2bf(acc[ai][bj][2] + bsv);
                    pk.w = f2bf(acc[ai][bj][3] + bsv);
                    int cs = (s >> 2) & 15;
                    int ps = (cs & 8) | ((cs & 3) << 1) | ((cs >> 2) & 1);
                    size_t off = ((size_t)(b_ * HEADS + h) * HDIM + d) * SEQ +
                                 (size_t)((s & ~63) | (ps << 2));
                    *reinterpret_cast<ushort4*>(Vto + off) = pk;
                }
            }
        }
    } else {
#pragma unroll
        for (int ai = 0; ai < AI; ai++) {
            int rowb = m0 + wr * (BM / 2) + ai * 16 + l16 * 4;
#pragma unroll
            for (int bj = 0; bj < BJ; bj++) {
                int col = n0 + wc * (BN / 2) + bj * 16 + l15;
                float bsv = bo[col];
#pragma unroll
                for (int r = 0; r < 4; r++)
                    Co[(size_t)(rowb + r) * EMBED + col] = acc[ai][bj][r] + bsv;
            }
        }
    }
}

// ---------------- causal flash attention (in-block 2-way KV split) ----------
// Round-19 verified version (~38 us, 90.89 total): shuffle-free common-path
// softmax, per-lane l partials, hoisted V ds_reads, P in registers via
// cvt_pk + chunk-permuted V. qi = su<16 ? su : 47-su (light pairs first).
__device__ __forceinline__ void stage_kv(const unsigned short* __restrict__ Kg,
                                         const unsigned short* __restrict__ Vg,
                                         int kv0, unsigned short* Ksb,
                                         unsigned short* Vsb, int tl) {
#pragma unroll
    for (int i = 0; i < 4; i++) {          // K tile [64 keys][64 d]
        int c = i * 128 + tl;
        int row = c >> 3;
        int lc = (c & 7) ^ (row & 7);
        g2l16(Kg + (size_t)(kv0 + row) * HDIM + lc * 8,
              Ksb + (i * 128 + (tl & ~63)) * 8);
    }
#pragma unroll
    for (int i = 0; i < 4; i++) {          // V^T tile [64 d][64 keys']
        int c = i * 128 + tl;
        int d = c >> 3;
        int lc = (c & 7) ^ (d & 7);
        g2l16(Vg + (size_t)d * SEQ + kv0 + lc * 8,
              Vsb + (i * 128 + (tl & ~63)) * 8);
    }
}

__global__ __launch_bounds__(256, 2)
void attn_kernel(const unsigned short* __restrict__ Q,
                 const unsigned short* __restrict__ Kk,
                 const unsigned short* __restrict__ Vt,
                 unsigned short* __restrict__ O) {
    __shared__ __attribute__((aligned(16))) unsigned short Ks[4][64 * 64];
    __shared__ __attribute__((aligned(16))) unsigned short Vs[4][64 * 64];

    const int t = threadIdx.x;
    const int lane = t & 63;
    const int w = t >> 6;
    const int wq = w >> 1;            // q-half
    const int wk = w & 1;             // KV way (tile parity)
    const int l15 = lane & 15, l16 = lane >> 4;

    const int id = blockIdx.x;
    const int xcd = id & 7;
    const int u = id >> 3;             // 0..127 within XCD
    const int bh = xcd * 4 + (u & 3);  // 4 heads per XCD -> 2 MB K/V in L2
    const int su = u >> 2;             // 0..31
    const int qi = (su < 16) ? su : 47 - su;
    const int q0 = qi * 64;
    const size_t base = (size_t)bh * SEQ * HDIM;
    const unsigned short* Kg = Kk + base;
    const unsigned short* Vg = Vt + base;
    const int qrow0 = q0 + wq * 32;

    short8 qf[2][2];
    {
        const unsigned short* Qg = Q + base + (size_t)qrow0 * HDIM;
#pragma unroll
        for (int qb = 0; qb < 2; qb++)
#pragma unroll
            for (int kc = 0; kc < 2; kc++)
                qf[qb][kc] = *reinterpret_cast<const short8*>(
                    Qg + (qb * 16 + l15) * HDIM + (kc * 4 + l16) * 8);
    }

    f32x4 oacc[2][4];
#pragma unroll
    for (int qb = 0; qb < 2; qb++)
#pragma unroll
        for (int nd = 0; nd < 4; nd++) oacc[qb][nd] = (f32x4){0.f, 0.f, 0.f, 0.f};
    float m_run[2] = {-1e30f, -1e30f};
    float l_run[2] = {0.f, 0.f};          // per-lane partial sums

    const int nt = qi + 1;
    const int nsuper = (nt + 1) >> 1;

    auto stagepair = [&](int ta, int tb) {
        if (t < 128) {
            if (ta < nt) stage_kv(Kg, Vg, ta * 64, Ks[ta & 3], Vs[ta & 3], t);
        } else {
            if (tb < nt) stage_kv(Kg, Vg, tb * 64, Ks[tb & 3], Vs[tb & 3], t - 128);
        }
    };

    auto qkt = [&](f32x4 (&sc)[2][4], const unsigned short* Kb) {
#pragma unroll
        for (int qb = 0; qb < 2; qb++)
#pragma unroll
            for (int kb = 0; kb < 4; kb++) sc[qb][kb] = (f32x4){0.f, 0.f, 0.f, 0.f};
#pragma unroll
        for (int kc = 0; kc < 2; kc++) {
            short8 ka[4];
#pragma unroll
            for (int kb = 0; kb < 4; kb++) {
                int row = kb * 16 + l15;
                ka[kb] = *reinterpret_cast<const short8*>(
                    Kb + row * 64 + (((kc * 4 + l16) ^ (row & 7)) << 3));
            }
            __builtin_amdgcn_s_setprio(1);
#pragma unroll
            for (int qb = 0; qb < 2; qb++)
#pragma unroll
                for (int kb = 0; kb < 4; kb++)
                    sc[qb][kb] = __builtin_amdgcn_mfma_f32_16x16x32_bf16(
                        ka[kb], qf[qb][kc], sc[qb][kb], 0, 0, 0);
            __builtin_amdgcn_s_setprio(0);
        }
    };

    auto softmax_pv = [&](f32x4 (&sc)[2][4], const unsigned short* Vb, bool diag) {
        // HOISTED V-fragment reads: issue all 8 ds_read_b128 now; their
        // latency hides under the softmax VALU chain below (G7).
        short8 vb[2][4];
#pragma unroll
        for (int m = 0; m < 2; m++)
#pragma unroll
            for (int nd = 0; nd < 4; nd++) {
                int row = nd * 16 + l15;
                vb[m][nd] = *reinterpret_cast<const short8*>(
                    Vb + row * 64 + (((m * 4 + l16) ^ (row & 7)) << 3));
            }
        if (diag) {
#pragma unroll
            for (int qb = 0; qb < 2; qb++) {
                const int qloc = wq * 32 + qb * 16 + l15;
#pragma unroll
                for (int kb = 0; kb < 4; kb++)
#pragma unroll
                    for (int r = 0; r < 4; r++) {
                        int kloc = kb * 16 + l16 * 4 + r;
                        sc[qb][kb][r] = (kloc > qloc) ? -1e30f : sc[qb][kb][r];
                    }
            }
        }
        float vmax[2];
        bool need = false;
#pragma unroll
        for (int qb = 0; qb < 2; qb++) {
            float mx = -1e30f;
#pragma unroll
            for (int kb = 0; kb < 4; kb++)
                mx = fmaxf(mx, fmaxf(fmaxf(sc[qb][kb][0], sc[qb][kb][1]),
                                     fmaxf(sc[qb][kb][2], sc[qb][kb][3])));
            vmax[qb] = mx;
            need = need || (mx > m_run[qb] + 8.0f);
        }
        if (__any(need)) {                 // rare: cross-lane work only here
#pragma unroll
            for (int qb = 0; qb < 2; qb++) {
                float mx = vmax[qb];
                mx = fmaxf(mx, __shfl_xor(mx, 16));
                mx = fmaxf(mx, __shfl_xor(mx, 32));
                float mn = fmaxf(m_run[qb], mx);
                float sf = __builtin_amdgcn_exp2f(m_run[qb] - mn);
                m_run[qb] = mn;
                l_run[qb] *= sf;
#pragma unroll
                for (int r = 0; r < 4; r++) {
                    float sfr = __shfl(sf, l16 * 4 + r);
#pragma unroll
                    for (int nd = 0; nd < 4; nd++) oacc[qb][nd][r] *= sfr;
                }
            }
        }
        short8 pa[2][2];
#pragma unroll
        for (int qb = 0; qb < 2; qb++) {
            float p[4][4];
            float ps = 0.f;
#pragma unroll
            for (int kb = 0; kb < 4; kb++)
#pragma unroll
                for (int r = 0; r < 4; r++) {
                    p[kb][r] = __builtin_amdgcn_exp2f(sc[qb][kb][r] - m_run[qb]);
                    ps += p[kb][r];
                }
            pa[qb][0] = mk8(cvt_pk_bf16(p[0][0], p[0][1]),
                            cvt_pk_bf16(p[0][2], p[0][3]),
                            cvt_pk_bf16(p[1][0], p[1][1]),
                            cvt_pk_bf16(p[1][2], p[1][3]));
            pa[qb][1] = mk8(cvt_pk_bf16(p[2][0], p[2][1]),
                            cvt_pk_bf16(p[2][2], p[2][3]),
                            cvt_pk_bf16(p[3][0], p[3][1]),
                            cvt_pk_bf16(p[3][2], p[3][3]));
            l_run[qb] += ps;               // per-lane partial; no shuffles
        }
        __builtin_amdgcn_s_setprio(1);
#pragma unroll
        for (int m = 0; m < 2; m++)
#pragma unroll
            for (int qb = 0; qb < 2; qb++)
#pragma unroll
                for (int nd = 0; nd < 4; nd++)
                    oacc[qb][nd] = __builtin_amdgcn_mfma_f32_16x16x32_bf16(
                        pa[qb][m], vb[m][nd], oacc[qb][nd], 0, 0, 0);
        __builtin_amdgcn_s_setprio(0);
    };

    f32x4 sc[2][4];

    stagepair(0, 1);
    asm volatile("s_waitcnt vmcnt(0)" ::: "memory");
    __builtin_amdgcn_s_barrier();
    asm volatile("" ::: "memory");
    stagepair(2, 3);
    int myt = wk;
    if (myt < nt) qkt(sc, Ks[myt & 3]);

    for (int j = 1; j < nsuper; j++) {
        if (myt < nt) softmax_pv(sc, Vs[myt & 3], false);
        asm volatile("s_waitcnt vmcnt(0)" ::: "memory");
        __builtin_amdgcn_s_barrier();
        asm volatile("" ::: "memory");
        stagepair(2 * j + 2, 2 * j + 3);
        int tc = 2 * j + wk;
        if (tc < nt) qkt(sc, Ks[tc & 3]);
        myt = tc;
    }
    if (myt < nt) softmax_pv(sc, Vs[myt & 3], myt == nt - 1);

    // ---- cross-way merge via LDS (aliases staging buffers; reads done) ----
    __syncthreads();
    float* po = reinterpret_cast<float*>(&Ks[0][0]);   // way-1 oacc, 16 KB
    float* pml = reinterpret_cast<float*>(&Vs[0][0]);  // way-1 m,l (per-lane)
    if (wk == 1) {
#pragma unroll
        for (int qb = 0; qb < 2; qb++) {
#pragma unroll
            for (int nd = 0; nd < 4; nd++)
                reinterpret_cast<f32x4*>(po)[(((wq << 1) | qb) * 4 + nd) * 64 + lane] =
                    oacc[qb][nd];
            pml[((((wq << 1) | qb) * 64) + lane) * 2]     = m_run[qb];
            pml[((((wq << 1) | qb) * 64) + lane) * 2 + 1] = l_run[qb];
        }
    }
    __syncthreads();
    if (wk == 0) {
        const int b_ = bh >> 4, h = bh & 15;
#pragma unroll
        for (int qb = 0; qb < 2; qb++) {
            float m1 = pml[((((wq << 1) | qb) * 64) + lane) * 2];
            float l1 = pml[((((wq << 1) | qb) * 64) + lane) * 2 + 1];
            float ms = fmaxf(m_run[qb], m1);
            float a0 = __builtin_amdgcn_exp2f(m_run[qb] - ms);
            float a1 = __builtin_amdgcn_exp2f(m1 - ms);
            float lmp = l_run[qb] * a0 + l1 * a1;
            lmp += __shfl_xor(lmp, 16);
            lmp += __shfl_xor(lmp, 32);
            f32x4 o1[4];
#pragma unroll
            for (int nd = 0; nd < 4; nd++)
                o1[nd] = reinterpret_cast<f32x4*>(po)[(((wq << 1) | qb) * 4 + nd) * 64 + lane];
            float li = 1.0f / lmp;
#pragma unroll
            for (int r = 0; r < 4; r++) {
                float a0r = __shfl(a0, l16 * 4 + r);
                float a1r = __shfl(a1, l16 * 4 + r);
                float lir = __shfl(li, l16 * 4 + r);
                int row = b_ * SEQ + qrow0 + qb * 16 + l16 * 4 + r;
#pragma unroll
                for (int nd = 0; nd < 4; nd++) {
                    float v = oacc[qb][nd][r] * a0r + o1[nd][r] * a1r;
                    O[(size_t)row * EMBED + h * 64 + nd * 16 + l15] = f2bf(v * lir);
                }
            }
        }
    }
}

extern "C" void kernel_launch(void* const* d_in, const int* in_sizes, int n_in,
                              void* d_out, int out_size, void* d_ws, size_t ws_size,
                              hipStream_t stream) {
    (void)in_sizes; (void)n_in; (void)out_size; (void)ws_size;
    const float* x  = (const float*)d_in[0];
    const float* Wq = (const float*)d_in[1];
    const float* bq = (const float*)d_in[2];
    const float* Wk = (const float*)d_in[3];
    const float* bk = (const float*)d_in[4];
    const float* Wv = (const float*)d_in[5];
    const float* bv = (const float*)d_in[6];
    const float* Wo = (const float*)d_in[7];
    const float* bo = (const float*)d_in[8];
    float* out = (float*)d_out;

    unsigned short* xb   = (unsigned short*)d_ws;
    unsigned short* Wqkv = xb + (size_t)NROWS * EMBED;          // [4][1024][1024]
    unsigned short* Wot  = Wqkv + (size_t)3 * EMBED * EMBED;    // = Wqkv[3]
    unsigned short* Qb   = Wot + (size_t)EMBED * EMBED;         // [b,h,s,d]
    unsigned short* Kb   = Qb + (size_t)NROWS * EMBED;
    unsigned short* Vtb  = Kb + (size_t)NROWS * EMBED;          // [b,h,d,s']
    unsigned short* attn = Vtb + (size_t)NROWS * EMBED;         // [b*s][1024]

    prep_kernel<<<8192, 256, 0, stream>>>(x, xb, Wq, Wk, Wv, Wo, Wqkv);

    gemm_kernel<0, 128, 128, 0><<<768, 256, 0, stream>>>(
        xb, Wqkv, EMBED, Qb, Kb, Vtb, bq, bk, bv, nullptr, nullptr);

    attn_kernel<<<1024, 256, 0, stream>>>(Qb, Kb, Vtb, attn);

    gemm_kernel<1, 64, 64, 1><<<1024, 256, 0, stream>>>(
        attn, Wot, EMBED, nullptr, nullptr, nullptr, nullptr, nullptr, nullptr,
        out, bo);
}